// Round 9
// baseline (191.349 us; speedup 1.0000x reference)
//
#include <hip/hip_runtime.h>
#include <hip/hip_bf16.h>

// ChannelDense: y[b,n,o] = tanh( sum_i x[b,n,i]*W[c[n],o,i] + bias[c[n],o] ) + x[b,n,o]
// B=128, N=2048, IN=OUT=256, 64 channels.
//
// R9 = R8 + (a) counted barrier: raw s_barrier with lgkmcnt(0) only -- no vmcnt
// drain, so y-stores and the p+2 x-prefetch stay in flight across the per-point
// barrier (T4); (b) 4 wgs/CU (1024 wgs, 8-point chunks) for phase stagger.
//  k0 sort: counting-sort by channel; perm packs (c<<16)|n; channels passthrough.
//  k1 wconv: W f32 -> bf16 linear image [c][o][k] in d_ws.
//  k2 main: 1024 wgs = 256 chunks (8 sorted points) x 4 b-quarters, XCD-chunked.
//    wg = 512 thr = 8 waves; wave owns a 32-o strip, W IN REGISTERS (wreg[2][8] =
//    64 VGPR), reloaded only on channel change. Per point: x quarter (32 b x 256 k)
//    in 2x16KB LDS dbuf; compute = pure {ds_read + reg MFMA}; stage_write(p+1) +
//    stage_load(p+2) before the tanh epilogue; ONE lgkm-only barrier per point.

#define N_SZ  2048
#define CHUNK 8

typedef __attribute__((ext_vector_type(8))) __bf16 bf16x8;
typedef __attribute__((ext_vector_type(4))) float  f32x4;

__device__ __forceinline__ float bf2f(unsigned u16) {
    union { unsigned u; float f; } v; v.u = u16 << 16;
    return v.f;
}
__device__ __forceinline__ float tanh_fast(float s) {
    float a = fabsf(s);
    float t = __expf(-2.0f * a);
    float r = (1.0f - t) * __builtin_amdgcn_rcpf(1.0f + t);
    return __builtin_copysignf(r, s);
}
__device__ __forceinline__ bf16x8 cvt8(float4 a, float4 b) {
    bf16x8 v;
    v[0] = (__bf16)a.x; v[1] = (__bf16)a.y; v[2] = (__bf16)a.z; v[3] = (__bf16)a.w;
    v[4] = (__bf16)b.x; v[5] = (__bf16)b.y; v[6] = (__bf16)b.z; v[7] = (__bf16)b.w;
    return v;
}
// LDS-only barrier: ds-writes visible wg-wide, but vmcnt (global loads/stores)
// NOT drained -- prefetches and y-stores fly across (T4 / m201 pattern).
__device__ __forceinline__ void wg_barrier_lds() {
    asm volatile("s_waitcnt lgkmcnt(0)" ::: "memory");
    __builtin_amdgcn_s_barrier();
    asm volatile("" ::: "memory");
}

// ---- k0: counting sort; perm[p] = (c<<16)|n; channels passthrough ----
__global__ __launch_bounds__(1024) void sort_kernel(const int* __restrict__ channels,
                                                    int* __restrict__ perm,
                                                    float* __restrict__ out_ch) {
    __shared__ int cnt[64], off[64];
    const int t = threadIdx.x;
    if (t < 64) cnt[t] = 0;
    __syncthreads();
    const int n0 = t, n1 = t + 1024;
    const int c0 = channels[n0], c1 = channels[n1];
    atomicAdd(&cnt[c0], 1);
    atomicAdd(&cnt[c1], 1);
    out_ch[n0] = (float)c0;
    out_ch[n1] = (float)c1;
    __syncthreads();
    if (t == 0) { int s = 0; for (int i = 0; i < 64; ++i) { off[i] = s; s += cnt[i]; } }
    __syncthreads();
    int p0 = atomicAdd(&off[c0], 1); perm[p0] = n0 | (c0 << 16);
    int p1 = atomicAdd(&off[c1], 1); perm[p1] = n1 | (c1 << 16);
}

// ---- k1: W f32 -> bf16 linear image ----
__global__ __launch_bounds__(256) void wconv_kernel(const float* __restrict__ w,
                                                    unsigned short* __restrict__ wsW) {
    const size_t t = (size_t)blockIdx.x * 256 + threadIdx.x;   // 524288 chunks of 8
    const float* src = w + t * 8;
    float4 f0 = *(const float4*)(src);
    float4 f1 = *(const float4*)(src + 4);
    bf16x8 v = cvt8(f0, f1);
    *(bf16x8*)(wsW + t * 8) = v;
}

// ---- k2: main ----
__global__ __launch_bounds__(512, 4) void channel_dense_kernel(
    const float* __restrict__ x, const int* __restrict__ perm,
    const unsigned short* __restrict__ wsW, const float* __restrict__ bias,
    float* __restrict__ y)
{
    __shared__ __align__(16) unsigned char sA[2][16384];  // [slab=8][r=32][64B] each

    const int g  = blockIdx.x;                 // 0..1023
    const int lg = (g & 7) * 128 + (g >> 3);   // XCD-chunked: XCD gets 32 chunks
    const int chunk   = lg >> 2;               // 0..255 -> points [chunk*8, +8)
    const int quarter = lg & 3;                // b rows quarter*32 .. +32
    const int tid  = threadIdx.x;
    const int lane = tid & 63, wv = tid >> 6;  // 8 waves
    const int lr   = lane & 15, lg4 = lane >> 4;

    // --- staging mapping: thread = (row sr 0..31, k-chunk sh 0..15 of 16 floats) ---
    const int sr = tid >> 4;
    const int sh = tid & 15;
    const int s_slab = sh >> 1;
    const int s_lin0 = sr * 64 + (sh & 1) * 32;
    const int s_swz  = ((sr & 7) << 4) ^ ((s_slab & 3) << 4);
    const int s_addr0 = s_slab * 2048 + ((s_lin0)      ^ s_swz);
    const int s_addr1 = s_slab * 2048 + ((s_lin0 + 16) ^ s_swz);

    float4 la0, la1, la2, la3;                 // 16 floats: x[row][sh*16 .. +16]
    auto stage_load = [&](int n_) {
        const float* p = x + ((size_t)(quarter * 32 + sr) * N_SZ + n_) * 256 + sh * 16;
        la0 = *(const float4*)(p);     la1 = *(const float4*)(p + 4);
        la2 = *(const float4*)(p + 8); la3 = *(const float4*)(p + 12);
    };
    auto stage_write = [&](int buf) {
        *(bf16x8*)(&sA[buf][s_addr0]) = cvt8(la0, la1);
        *(bf16x8*)(&sA[buf][s_addr1]) = cvt8(la2, la3);
    };

    const int p0 = chunk * CHUNK;

    // prologue: point 0 -> LDS buf0; point 1 -> regs
    int pv_cur = perm[p0];
    stage_load(pv_cur & 0xffff);
    stage_write(0);
    int pv_nxt = perm[p0 + 1];
    stage_load(pv_nxt & 0xffff);
    wg_barrier_lds();

    bf16x8 wreg[2][8];                         // W[c][wv*32 + {0,16}+lr][.]
    float4 bv0, bv1;
    int c_cur = -1;
    int cur = 0;
    const int o0 = wv * 32 + lg4 * 4;          // epilogue o base (mo=0)

    for (int i = 0; i < CHUNK; ++i) {
        const int n = pv_cur & 0xffff;
        const int c = pv_cur >> 16;
        if (c != c_cur) {                      // wg-uniform branch
            c_cur = c;
            const unsigned short* wl = wsW + (((size_t)c * 256 + wv * 32 + lr) << 8) + lg4 * 8;
            #pragma unroll
            for (int kt = 0; kt < 8; ++kt) {
                wreg[0][kt] = *(const bf16x8*)(wl + kt * 32);
                wreg[1][kt] = *(const bf16x8*)(wl + 16 * 256 + kt * 32);
            }
            bv0 = *(const float4*)(bias + c * 256 + o0);
            bv1 = *(const float4*)(bias + c * 256 + o0 + 16);
        }

        // ---- compute: 16 ds_read_b128 + 32 MFMA, all operands reg/LDS ----
        f32x4 acc[2][2] = {};
        #pragma unroll
        for (int kt = 0; kt < 8; ++kt) {
            const int lb = (lr * 64 + lg4 * 16) ^ ((lr & 7) << 4) ^ ((kt & 3) << 4);
            bf16x8 xf0 = *(const bf16x8*)(&sA[cur][kt * 2048 + lb]);
            bf16x8 xf1 = *(const bf16x8*)(&sA[cur][kt * 2048 + 1024 + lb]);
            acc[0][0] = __builtin_amdgcn_mfma_f32_16x16x32_bf16(wreg[0][kt], xf0, acc[0][0], 0, 0, 0);
            acc[0][1] = __builtin_amdgcn_mfma_f32_16x16x32_bf16(wreg[0][kt], xf1, acc[0][1], 0, 0, 0);
            acc[1][0] = __builtin_amdgcn_mfma_f32_16x16x32_bf16(wreg[1][kt], xf0, acc[1][0], 0, 0, 0);
            acc[1][1] = __builtin_amdgcn_mfma_f32_16x16x32_bf16(wreg[1][kt], xf1, acc[1][1], 0, 0, 0);
        }

        // ---- staging for the pipeline BEFORE the epilogue (tanh covers latency) ----
        if (i < CHUNK - 1) {
            stage_write(cur ^ 1);              // la holds point p+1 (loaded long ago)
            if (i < CHUNK - 2) {
                pv_cur = pv_nxt;
                pv_nxt = perm[p0 + i + 2];
                stage_load(pv_nxt & 0xffff);   // lands during epilogue / next compute
            } else {
                pv_cur = pv_nxt;
            }
        }

        // ---- epilogue: bias + tanh + residual(LDS) + float4 stores ----
        #pragma unroll
        for (int mo = 0; mo < 2; ++mo) {
            const float4 bv = mo ? bv1 : bv0;
            const int oo    = o0 + mo * 16;
            const int s     = oo >> 5;
            const int intra = (oo & 31) * 2;
            #pragma unroll
            for (int nb = 0; nb < 2; ++nb) {
                const int rl = nb * 16 + lr;
                const int b  = quarter * 32 + rl;
                const int rbyte = s * 2048 +
                    ((rl * 64 + intra) ^ ((rl & 7) << 4) ^ ((s & 3) << 4));
                uint2 rv = *(const uint2*)(&sA[cur][rbyte]);
                float4 o;
                o.x = tanh_fast(acc[mo][nb][0] + bv.x) + bf2f(rv.x & 0xffffu);
                o.y = tanh_fast(acc[mo][nb][1] + bv.y) + bf2f(rv.x >> 16);
                o.z = tanh_fast(acc[mo][nb][2] + bv.z) + bf2f(rv.y & 0xffffu);
                o.w = tanh_fast(acc[mo][nb][3] + bv.w) + bf2f(rv.y >> 16);
                *(float4*)(y + ((size_t)b * N_SZ + n) * 256 + oo) = o;
            }
        }

        if (i < CHUNK - 1) wg_barrier_lds();   // lgkm-only: stores/prefetch fly on
        cur ^= 1;
    }
}

extern "C" void kernel_launch(void* const* d_in, const int* in_sizes, int n_in,
                              void* d_out, int out_size, void* d_ws, size_t ws_size,
                              hipStream_t stream) {
    const float* x        = (const float*)d_in[0];
    const int*   channels = (const int*)d_in[1];
    const float* weight   = (const float*)d_in[2];
    const float* bias     = (const float*)d_in[3];
    float* y = (float*)d_out;

    unsigned short* wsW = (unsigned short*)d_ws;             // 8 MB bf16 W image
    int* perm = (int*)((unsigned char*)d_ws + (64u << 17));  // + 8KB perm

    sort_kernel<<<dim3(1), dim3(1024), 0, stream>>>(
        channels, perm, y + (size_t)128 * N_SZ * 256);
    wconv_kernel<<<dim3(2048), dim3(256), 0, stream>>>(weight, wsW);
    channel_dense_kernel<<<dim3(1024), dim3(512), 0, stream>>>(
        x, perm, wsW, bias, y);
}